// Round 5
// baseline (153.643 us; speedup 1.0000x reference)
//
#include <hip/hip_runtime.h>
#include <hip/hip_bf16.h>
#include <math.h>

#define DIMX 1024
#define SEQ  1024
#define HD   64
#define QH   2
#define TH   14
#define QKVN 2688   // 3*896
#define LN_EPS 1e-5f

typedef __bf16 bf16x8 __attribute__((ext_vector_type(8)));
typedef float  f32x4  __attribute__((ext_vector_type(4)));
typedef unsigned short u16x8 __attribute__((ext_vector_type(8)));

__device__ inline unsigned short f2b_rne(float f) {
  unsigned int u = __float_as_uint(f);
  unsigned int r = (u + 0x7FFF + ((u >> 16) & 1)) >> 16;
  return (unsigned short)r;
}

__device__ inline float waveRedSum(float v) {
  #pragma unroll
  for (int off = 32; off; off >>= 1) v += __shfl_xor(v, off, 64);
  return v;
}

// ---------------- fused f32 -> bf16 convert for x, Wq|Wk|Wv, Wo ----------------
// segments (f32 elems): x 1048576 | wq 917504 | wk 917504 | wv 917504 | wo 1048576
__global__ __launch_bounds__(256) void k_f2b_all(
    const float* __restrict__ x, const float* __restrict__ wq,
    const float* __restrict__ wk, const float* __restrict__ wv,
    const float* __restrict__ wo,
    unsigned short* __restrict__ x_bf, unsigned short* __restrict__ wqkv_bf,
    unsigned short* __restrict__ wo_bf) {
  long i = ((long)blockIdx.x * 256 + threadIdx.x) * 4;
  float4 v;
  unsigned short* dst;
  if (i < 1048576) {
    v = *reinterpret_cast<const float4*>(x + i);
    dst = x_bf + i;
  } else if (i < 3801088) {
    long j = i - 1048576;
    const float* s = (j < 917504) ? wq + j
                   : (j < 1835008) ? wk + (j - 917504)
                                   : wv + (j - 1835008);
    v = *reinterpret_cast<const float4*>(s);
    dst = wqkv_bf + j;
  } else {
    long j = i - 3801088;
    v = *reinterpret_cast<const float4*>(wo + j);
    dst = wo_bf + j;
  }
  ushort4 o;
  o.x = f2b_rne(v.x); o.y = f2b_rne(v.y); o.z = f2b_rne(v.z); o.w = f2b_rne(v.w);
  *reinterpret_cast<ushort4*>(dst) = o;
}

// ---------------- quantum prep ----------------
// qs = tanh(LN(xh@qsW^T+b)); amp=qs[:64], phase=qs[64:]
// qcs[h][i][0:64] = amp*cos(phase*f+s), [64:128] = amp*sin(phase*f+s)   (query side)
// kcs[h][j][0:64] = amp*cos(phase*f),   [64:128] = amp*sin(phase*f)     (key side)
__global__ __launch_bounds__(128) void k_qprep(
    const float* __restrict__ x, const float* __restrict__ qsW,
    const float* __restrict__ qsb, const float* __restrict__ lng,
    const float* __restrict__ lnb, const float* __restrict__ qfreq,
    const float* __restrict__ qshift,
    unsigned short* __restrict__ qcs, unsigned short* __restrict__ kcs) {
  int b = blockIdx.x; int h = b >> 10; int i = b & 1023;
  int o = threadIdx.x;  // 0..127
  __shared__ float xrow[HD];
  __shared__ float red[4];
  __shared__ float qsv[128];
  if (o < HD) xrow[o] = x[i * DIMX + h * HD + o];
  __syncthreads();
  float s = qsb[o];
  #pragma unroll
  for (int d = 0; d < HD; d += 4) {
    float4 w = *reinterpret_cast<const float4*>(qsW + o * HD + d);
    float4 xv = *reinterpret_cast<const float4*>(&xrow[d]);
    s += xv.x * w.x + xv.y * w.y + xv.z * w.z + xv.w * w.w;
  }
  int wid = o >> 6, lane = o & 63;
  float ws = waveRedSum(s);
  if (lane == 0) red[wid] = ws;
  __syncthreads();
  float mu = (red[0] + red[1]) * (1.0f / 128.0f);
  float dv = s - mu;
  float ws2 = waveRedSum(dv * dv);
  if (lane == 0) red[2 + wid] = ws2;
  __syncthreads();
  float var = (red[2] + red[3]) * (1.0f / 128.0f);
  float y = dv * rsqrtf(var + LN_EPS) * lng[o] + lnb[o];
  qsv[o] = tanhf(y);
  __syncthreads();
  float freq = qfreq[h], shift = qshift[h];
  size_t base = ((size_t)h * 1024 + i) * 128;
  if (o < HD) {
    float amp = qsv[o];
    float a = qsv[64 + o] * freq + shift;
    float sn, cs;
    __sincosf(a, &sn, &cs);
    qcs[base + o]      = f2b_rne(amp * cs);
    qcs[base + 64 + o] = f2b_rne(amp * sn);
  } else {
    int d = o - 64;
    float amp = qsv[d];
    float bAng = qsv[64 + d] * freq;
    float sn, cs;
    __sincosf(bAng, &sn, &cs);
    kcs[base + d]      = f2b_rne(amp * cs);
    kcs[base + 64 + d] = f2b_rne(amp * sn);
  }
}

// ---------------- 64-col block transpose: src[kv][col0+h*64+d] -> dst[h][d][kv] ----------------
__global__ __launch_bounds__(256) void k_tr64(const unsigned short* __restrict__ src, int ld,
                                              int col0, unsigned short* __restrict__ dst) {
  int h = blockIdx.y, kv0 = blockIdx.x * 64;
  int t = threadIdx.x;
  __shared__ unsigned short tile[64][72];
  #pragma unroll
  for (int pass = 0; pass < 2; ++pass) {
    int s = pass * 256 + t;
    int r = s >> 3, c8 = (s & 7) * 8;
    u16x8 v = *reinterpret_cast<const u16x8*>(src + (size_t)(kv0 + r) * ld + col0 + h * 64 + c8);
    *reinterpret_cast<u16x8*>(&tile[r][c8]) = v;
  }
  __syncthreads();
  #pragma unroll
  for (int pass = 0; pass < 2; ++pass) {
    int s = pass * 256 + t;
    int d = s >> 3, k8 = (s & 7) * 8;
    u16x8 o;
    #pragma unroll
    for (int j = 0; j < 8; ++j) o[j] = tile[k8 + j][d];
    *reinterpret_cast<u16x8*>(dst + (size_t)h * 65536 + (size_t)d * 1024 + kv0 + k8) = o;
  }
}

// ---------------- fused flash attention ----------------
// Per block: one head, 64 q-rows, loop over 16 kv-tiles of 64.
// Q rows: Qb + h*q_hstep + q*ldq (bf16, DQK wide). K likewise.
// V^T rows: Vtb + h*65536 + d*1024 + kv  (bf16). Out: Outb + h*64 + q*DIMX + d (bf16).
// scale 1/8 folded into exp. Online softmax, P via LDS round-trip.
template <int DQK>
__global__ __launch_bounds__(256) void k_fattn(
    const unsigned short* __restrict__ Qb, long q_hstep, int ldq,
    const unsigned short* __restrict__ Kb, long k_hstep, int ldk,
    const unsigned short* __restrict__ Vtb,
    unsigned short* __restrict__ Outb) {
  const int LQ = DQK + 8;          // padded LDS row stride (shorts)
  __shared__ unsigned short Qs[64 * LQ];
  __shared__ unsigned short Ks[64 * LQ];
  __shared__ unsigned short Vs[64 * 72];
  __shared__ unsigned short Ps[64 * 72];
  int h = blockIdx.y;
  int q0 = blockIdx.x * 64;
  int t = threadIdx.x, lane = t & 63, w = t >> 6;
  const unsigned short* Qp = Qb + (size_t)h * q_hstep;
  const unsigned short* Kp = Kb + (size_t)h * k_hstep;
  const unsigned short* Vp = Vtb + (size_t)h * 65536;
  // stage Q tile (64 x DQK)
  for (int s = t; s < 64 * DQK / 8; s += 256) {
    int r = s / (DQK / 8), c8 = (s % (DQK / 8)) * 8;
    u16x8 v = *reinterpret_cast<const u16x8*>(Qp + (size_t)(q0 + r) * ldq + c8);
    *reinterpret_cast<u16x8*>(&Qs[r * LQ + c8]) = v;
  }
  f32x4 acc_o[4] = {};
  float mrow[4] = {-1e30f, -1e30f, -1e30f, -1e30f};
  float lrow[4] = {0.f, 0.f, 0.f, 0.f};
  int g = lane >> 4, li = lane & 15;
  for (int jt = 0; jt < 16; ++jt) {
    int j0 = jt * 64;
    __syncthreads();   // prev iteration's Ks/Vs reads done (also covers initial Qs)
    for (int s = t; s < 64 * DQK / 8; s += 256) {
      int r = s / (DQK / 8), c8 = (s % (DQK / 8)) * 8;
      u16x8 v = *reinterpret_cast<const u16x8*>(Kp + (size_t)(j0 + r) * ldk + c8);
      *reinterpret_cast<u16x8*>(&Ks[r * LQ + c8]) = v;
    }
    for (int s = t; s < 512; s += 256) {
      int d = s >> 3, c8 = (s & 7) * 8;
      u16x8 v = *reinterpret_cast<const u16x8*>(Vp + (size_t)d * 1024 + j0 + c8);
      *reinterpret_cast<u16x8*>(&Vs[d * 72 + c8]) = v;
    }
    __syncthreads();
    // scores: wave w owns q rows w*16..w*16+15; 4 kv n-tiles
    f32x4 s_acc[4] = {};
    #pragma unroll
    for (int kk = 0; kk < DQK / 32; ++kk) {
      bf16x8 aq = *reinterpret_cast<const bf16x8*>(&Qs[(w * 16 + li) * LQ + kk * 32 + g * 8]);
      #pragma unroll
      for (int n = 0; n < 4; ++n) {
        bf16x8 bk = *reinterpret_cast<const bf16x8*>(&Ks[(n * 16 + li) * LQ + kk * 32 + g * 8]);
        s_acc[n] = __builtin_amdgcn_mfma_f32_16x16x32_bf16(aq, bk, s_acc[n], 0, 0, 0);
      }
    }
    // online softmax (C-layout: row = g*4+r, col = li + n*16)
    #pragma unroll
    for (int r = 0; r < 4; ++r) {
      float tm = fmaxf(fmaxf(s_acc[0][r], s_acc[1][r]), fmaxf(s_acc[2][r], s_acc[3][r]));
      #pragma unroll
      for (int m = 1; m < 16; m <<= 1) tm = fmaxf(tm, __shfl_xor(tm, m, 64));
      float mn = fmaxf(mrow[r], tm);
      float sf = __expf((mrow[r] - mn) * 0.125f);
      mrow[r] = mn;
      lrow[r] *= sf;
      #pragma unroll
      for (int n = 0; n < 4; ++n) acc_o[n][r] *= sf;
      float rs = 0.f;
      #pragma unroll
      for (int n = 0; n < 4; ++n) {
        float p = __expf((s_acc[n][r] - mn) * 0.125f);
        s_acc[n][r] = p;
        rs += p;
      }
      #pragma unroll
      for (int m = 1; m < 16; m <<= 1) rs += __shfl_xor(rs, m, 64);
      lrow[r] += rs;
    }
    #pragma unroll
    for (int n = 0; n < 4; ++n)
      #pragma unroll
      for (int r = 0; r < 4; ++r)
        Ps[(w * 16 + g * 4 + r) * 72 + n * 16 + li] = f2b_rne(s_acc[n][r]);
    __syncthreads();   // cross-lane P visibility
    // PV: A = P (q rows), B = Vs (d rows, kv k)
    #pragma unroll
    for (int kk = 0; kk < 2; ++kk) {
      bf16x8 ap = *reinterpret_cast<const bf16x8*>(&Ps[(w * 16 + li) * 72 + kk * 32 + g * 8]);
      #pragma unroll
      for (int n = 0; n < 4; ++n) {
        bf16x8 bv = *reinterpret_cast<const bf16x8*>(&Vs[(n * 16 + li) * 72 + kk * 32 + g * 8]);
        acc_o[n] = __builtin_amdgcn_mfma_f32_16x16x32_bf16(ap, bv, acc_o[n], 0, 0, 0);
      }
    }
  }
  unsigned short* Op = Outb + (size_t)h * 64;
  #pragma unroll
  for (int r = 0; r < 4; ++r) {
    float inv = 1.0f / lrow[r];
    int qr = q0 + w * 16 + g * 4 + r;
    #pragma unroll
    for (int n = 0; n < 4; ++n)
      Op[(size_t)qr * DIMX + n * 16 + li] = f2b_rne(acc_o[n][r] * inv);
  }
}

// ---------------- batched bf16 MFMA GEMM: C = A * B^T (+bias), strided ----------------
template <int HAS_BIAS, int BF16_OUT>
__global__ __launch_bounds__(256) void k_bgemm(
    const unsigned short* __restrict__ A, const unsigned short* __restrict__ B,
    void* __restrict__ Cv, const float* __restrict__ bias,
    int K, int lda, int ldb, int ldc,
    long a_batch, long b_batch, long c_batch) {
  const int LDT = 72;  // padded LDS row stride (shorts)
  __shared__ unsigned short As[64 * LDT];
  __shared__ unsigned short Bs[64 * LDT];
  int t = threadIdx.x;
  int lane = t & 63, w = t >> 6;
  int wr = w >> 1, wc = w & 1;
  int mb = blockIdx.y * 64, nb = blockIdx.x * 64;
  const unsigned short* Ab = A + (size_t)blockIdx.z * a_batch;
  const unsigned short* Bb = B + (size_t)blockIdx.z * b_batch;
  f32x4 acc[2][2] = {};
  int r0 = t >> 3;         // 0..31
  int c0 = (t & 7) * 8;    // element offset
  for (int kb = 0; kb < K; kb += 64) {
    bf16x8 av0 = *reinterpret_cast<const bf16x8*>(Ab + (size_t)(mb + r0) * lda + kb + c0);
    bf16x8 av1 = *reinterpret_cast<const bf16x8*>(Ab + (size_t)(mb + r0 + 32) * lda + kb + c0);
    bf16x8 bv0 = *reinterpret_cast<const bf16x8*>(Bb + (size_t)(nb + r0) * ldb + kb + c0);
    bf16x8 bv1 = *reinterpret_cast<const bf16x8*>(Bb + (size_t)(nb + r0 + 32) * ldb + kb + c0);
    __syncthreads();
    *reinterpret_cast<bf16x8*>(&As[r0 * LDT + c0]) = av0;
    *reinterpret_cast<bf16x8*>(&As[(r0 + 32) * LDT + c0]) = av1;
    *reinterpret_cast<bf16x8*>(&Bs[r0 * LDT + c0]) = bv0;
    *reinterpret_cast<bf16x8*>(&Bs[(r0 + 32) * LDT + c0]) = bv1;
    __syncthreads();
    #pragma unroll
    for (int kk = 0; kk < 2; ++kk) {
      bf16x8 af[2], bfr[2];
      #pragma unroll
      for (int m = 0; m < 2; ++m)
        af[m] = *reinterpret_cast<const bf16x8*>(
            &As[(wr * 32 + m * 16 + (lane & 15)) * LDT + kk * 32 + (lane >> 4) * 8]);
      #pragma unroll
      for (int n = 0; n < 2; ++n)
        bfr[n] = *reinterpret_cast<const bf16x8*>(
            &Bs[(wc * 32 + n * 16 + (lane & 15)) * LDT + kk * 32 + (lane >> 4) * 8]);
      #pragma unroll
      for (int m = 0; m < 2; ++m)
        #pragma unroll
        for (int n = 0; n < 2; ++n)
          acc[m][n] = __builtin_amdgcn_mfma_f32_16x16x32_bf16(af[m], bfr[n], acc[m][n], 0, 0, 0);
    }
  }
  #pragma unroll
  for (int m = 0; m < 2; ++m) {
    int row0 = mb + wr * 32 + m * 16 + (lane >> 4) * 4;
    #pragma unroll
    for (int n = 0; n < 2; ++n) {
      int col = nb + wc * 32 + n * 16 + (lane & 15);
      float bval = HAS_BIAS ? bias[col] : 0.0f;
      #pragma unroll
      for (int r = 0; r < 4; ++r) {
        size_t idx = (size_t)blockIdx.z * c_batch + (size_t)(row0 + r) * ldc + col;
        if (BF16_OUT) ((unsigned short*)Cv)[idx] = f2b_rne(acc[m][n][r] + bval);
        else          ((float*)Cv)[idx] = acc[m][n][r] + bval;
      }
    }
  }
}

extern "C" void kernel_launch(void* const* d_in, const int* in_sizes, int n_in,
                              void* d_out, int out_size, void* d_ws, size_t ws_size,
                              hipStream_t stream) {
  const float* x      = (const float*)d_in[0];
  const float* qsW    = (const float*)d_in[1];
  const float* qsb    = (const float*)d_in[2];
  const float* lng    = (const float*)d_in[3];
  const float* lnb    = (const float*)d_in[4];
  const float* qfreq  = (const float*)d_in[5];
  const float* qshift = (const float*)d_in[6];
  const float* Wq     = (const float*)d_in[7];
  const float* Wk     = (const float*)d_in[8];
  const float* Wv     = (const float*)d_in[9];
  const float* Wo     = (const float*)d_in[10];
  const float* bo     = (const float*)d_in[11];
  float* out = (float*)d_out;

  char* ws = (char*)d_ws;
  size_t off = 0;
  auto alloc = [&](size_t bytes) { char* p = ws + off; off += (bytes + 255) & ~(size_t)255; return p; };
  unsigned short* x_bf      = (unsigned short*)alloc((size_t)SEQ * DIMX * 2);
  unsigned short* wqkv_bf   = (unsigned short*)alloc((size_t)QKVN * DIMX * 2);
  unsigned short* wo_bf     = (unsigned short*)alloc((size_t)DIMX * DIMX * 2);
  unsigned short* concat_bf = (unsigned short*)alloc((size_t)SEQ * DIMX * 2);
  unsigned short* qkv_bf    = (unsigned short*)alloc((size_t)SEQ * QKVN * 2);
  unsigned short* qcs       = (unsigned short*)alloc((size_t)QH * SEQ * 128 * 2);
  unsigned short* kcs       = (unsigned short*)alloc((size_t)QH * SEQ * 128 * 2);
  unsigned short* vt        = (unsigned short*)alloc((size_t)TH * HD * SEQ * 2);
  unsigned short* xt        = (unsigned short*)alloc((size_t)QH * HD * SEQ * 2);

  k_f2b_all<<<4736, 256, 0, stream>>>(x, Wq, Wk, Wv, Wo, x_bf, wqkv_bf, wo_bf);
  k_qprep<<<QH * SEQ, 128, 0, stream>>>(x, qsW, qsb, lng, lnb, qfreq, qshift, qcs, kcs);

  // QKV projection -> bf16 qkv
  k_bgemm<0, 1><<<dim3(QKVN / 64, SEQ / 64, 1), 256, 0, stream>>>(
      x_bf, wqkv_bf, qkv_bf, nullptr, DIMX, DIMX, DIMX, QKVN, 0, 0, 0);

  k_tr64<<<dim3(16, TH), 256, 0, stream>>>(qkv_bf, QKVN, 1792, vt);
  k_tr64<<<dim3(16, QH), 256, 0, stream>>>(x_bf, DIMX, 0, xt);

  // fused attention: quantum heads (DQK=128, V = x), trad heads (DQK=64, V from qkv)
  k_fattn<128><<<dim3(16, QH), 256, 0, stream>>>(
      qcs, (long)SEQ * 128, 128, kcs, (long)SEQ * 128, 128, xt, concat_bf);
  k_fattn<64><<<dim3(16, TH), 256, 0, stream>>>(
      qkv_bf, 64, QKVN, qkv_bf + 896, 64, QKVN, vt, concat_bf + 128);

  // output projection
  k_bgemm<1, 0><<<dim3(DIMX / 64, SEQ / 64, 1), 256, 0, stream>>>(
      concat_bf, wo_bf, out, bo, DIMX, DIMX, DIMX, DIMX, 0, 0, 0);
}

// Round 6
// 86.184 us; speedup vs baseline: 1.7827x; 1.7827x over previous
//
#include <hip/hip_runtime.h>
#include <hip/hip_bf16.h>
#include <math.h>

#define DIMX 1024
#define SEQ  1024
#define HD   64
#define QH   2
#define TH   14
#define QKVN 2688   // 3*896
#define LN_EPS 1e-5f
#define NSPLIT 4

typedef __bf16 bf16x8 __attribute__((ext_vector_type(8)));
typedef float  f32x4  __attribute__((ext_vector_type(4)));
typedef unsigned short u16x8 __attribute__((ext_vector_type(8)));

__device__ inline unsigned short f2b_rne(float f) {
  unsigned int u = __float_as_uint(f);
  unsigned int r = (u + 0x7FFF + ((u >> 16) & 1)) >> 16;
  return (unsigned short)r;
}

__device__ inline float waveRedSum(float v) {
  #pragma unroll
  for (int off = 32; off; off >>= 1) v += __shfl_xor(v, off, 64);
  return v;
}

// ---------------- fused f32 -> bf16 convert for x, Wq|Wk|Wv, Wo ----------------
__global__ __launch_bounds__(256) void k_f2b_all(
    const float* __restrict__ x, const float* __restrict__ wq,
    const float* __restrict__ wk, const float* __restrict__ wv,
    const float* __restrict__ wo,
    unsigned short* __restrict__ x_bf, unsigned short* __restrict__ wqkv_bf,
    unsigned short* __restrict__ wo_bf) {
  long i = ((long)blockIdx.x * 256 + threadIdx.x) * 4;
  float4 v;
  unsigned short* dst;
  if (i < 1048576) {
    v = *reinterpret_cast<const float4*>(x + i);
    dst = x_bf + i;
  } else if (i < 3801088) {
    long j = i - 1048576;
    const float* s = (j < 917504) ? wq + j
                   : (j < 1835008) ? wk + (j - 917504)
                                   : wv + (j - 1835008);
    v = *reinterpret_cast<const float4*>(s);
    dst = wqkv_bf + j;
  } else {
    long j = i - 3801088;
    v = *reinterpret_cast<const float4*>(wo + j);
    dst = wo_bf + j;
  }
  ushort4 o;
  o.x = f2b_rne(v.x); o.y = f2b_rne(v.y); o.z = f2b_rne(v.z); o.w = f2b_rne(v.w);
  *reinterpret_cast<ushort4*>(dst) = o;
}

// ---------------- quantum prep ----------------
__global__ __launch_bounds__(128) void k_qprep(
    const float* __restrict__ x, const float* __restrict__ qsW,
    const float* __restrict__ qsb, const float* __restrict__ lng,
    const float* __restrict__ lnb, const float* __restrict__ qfreq,
    const float* __restrict__ qshift,
    unsigned short* __restrict__ qcs, unsigned short* __restrict__ kcs) {
  int b = blockIdx.x; int h = b >> 10; int i = b & 1023;
  int o = threadIdx.x;  // 0..127
  __shared__ float xrow[HD];
  __shared__ float red[4];
  __shared__ float qsv[128];
  if (o < HD) xrow[o] = x[i * DIMX + h * HD + o];
  __syncthreads();
  float s = qsb[o];
  #pragma unroll
  for (int d = 0; d < HD; d += 4) {
    float4 w = *reinterpret_cast<const float4*>(qsW + o * HD + d);
    float4 xv = *reinterpret_cast<const float4*>(&xrow[d]);
    s += xv.x * w.x + xv.y * w.y + xv.z * w.z + xv.w * w.w;
  }
  int wid = o >> 6, lane = o & 63;
  float ws = waveRedSum(s);
  if (lane == 0) red[wid] = ws;
  __syncthreads();
  float mu = (red[0] + red[1]) * (1.0f / 128.0f);
  float dv = s - mu;
  float ws2 = waveRedSum(dv * dv);
  if (lane == 0) red[2 + wid] = ws2;
  __syncthreads();
  float var = (red[2] + red[3]) * (1.0f / 128.0f);
  float y = dv * rsqrtf(var + LN_EPS) * lng[o] + lnb[o];
  qsv[o] = tanhf(y);
  __syncthreads();
  float freq = qfreq[h], shift = qshift[h];
  size_t base = ((size_t)h * 1024 + i) * 128;
  if (o < HD) {
    float amp = qsv[o];
    float a = qsv[64 + o] * freq + shift;
    float sn, cs;
    __sincosf(a, &sn, &cs);
    qcs[base + o]      = f2b_rne(amp * cs);
    qcs[base + 64 + o] = f2b_rne(amp * sn);
  } else {
    int d = o - 64;
    float amp = qsv[d];
    float bAng = qsv[64 + d] * freq;
    float sn, cs;
    __sincosf(bAng, &sn, &cs);
    kcs[base + d]      = f2b_rne(amp * cs);
    kcs[base + 64 + d] = f2b_rne(amp * sn);
  }
}

// ---------------- 64-col block transpose: src[kv][col0+h*64+d] -> dst[h][d][kv] ----------------
__global__ __launch_bounds__(256) void k_tr64(const unsigned short* __restrict__ src, int ld,
                                              int col0, unsigned short* __restrict__ dst) {
  int h = blockIdx.y, kv0 = blockIdx.x * 64;
  int t = threadIdx.x;
  __shared__ unsigned short tile[64][72];
  #pragma unroll
  for (int pass = 0; pass < 2; ++pass) {
    int s = pass * 256 + t;
    int r = s >> 3, c8 = (s & 7) * 8;
    u16x8 v = *reinterpret_cast<const u16x8*>(src + (size_t)(kv0 + r) * ld + col0 + h * 64 + c8);
    *reinterpret_cast<u16x8*>(&tile[r][c8]) = v;
  }
  __syncthreads();
  #pragma unroll
  for (int pass = 0; pass < 2; ++pass) {
    int s = pass * 256 + t;
    int d = s >> 3, k8 = (s & 7) * 8;
    u16x8 o;
    #pragma unroll
    for (int j = 0; j < 8; ++j) o[j] = tile[k8 + j][d];
    *reinterpret_cast<u16x8*>(dst + (size_t)h * 65536 + (size_t)d * 1024 + kv0 + k8) = o;
  }
}

// ---------------- fused flash attention, kv-split ----------------
// Block: (q-tile, head, split). 64 q rows, 4 kv-tiles of 64 (256 kv). Double-buffered
// K/V LDS staging via registers; one barrier per tile. Outputs UNNORMALIZED partials:
// pout[(lh*NSPLIT+split)][q][64] f32 and pml[...][q][{m,l}].
template <int DQK>
__global__ __launch_bounds__(256) void k_fattn(
    const unsigned short* __restrict__ Qb, long q_hstep, int ldq,
    const unsigned short* __restrict__ Kb, long k_hstep, int ldk,
    const unsigned short* __restrict__ Vtb, long v_hstep, int lh0,
    float* __restrict__ pout, float* __restrict__ pml) {
  const int LQ = DQK + 8;
  const int KREG = DQK / 32;
  __shared__ unsigned short Qs[64 * LQ];
  __shared__ unsigned short Ks[2][64 * LQ];
  __shared__ unsigned short Vs[2][64 * 72];
  __shared__ unsigned short Ps[64 * 72];
  int h = blockIdx.y;
  int q0 = blockIdx.x * 64;
  int split = blockIdx.z;
  int kv0 = split * 256;
  int t = threadIdx.x, lane = t & 63, w = t >> 6;
  int g = lane >> 4, li = lane & 15;
  const unsigned short* Qp = Qb + (size_t)h * q_hstep;
  const unsigned short* Kp = Kb + (size_t)h * k_hstep;
  const unsigned short* Vp = Vtb + (size_t)h * v_hstep;

  // per-wave Q staging: wave w stages (and later reads) rows w*16..w*16+15 only
  #pragma unroll
  for (int i = 0; i < DQK / 32; ++i) {
    int s = i * 64 + lane;
    int r = s / (DQK / 8), c8 = (s % (DQK / 8)) * 8;
    u16x8 v = *reinterpret_cast<const u16x8*>(Qp + (size_t)(q0 + w * 16 + r) * ldq + c8);
    *reinterpret_cast<u16x8*>(&Qs[(w * 16 + r) * LQ + c8]) = v;
  }

  u16x8 kreg[KREG], vreg[2];
  auto loadKV = [&](int tile) {
    int j0 = kv0 + tile * 64;
    #pragma unroll
    for (int i = 0; i < KREG; ++i) {
      int s = i * 256 + t;
      int r = s / (DQK / 8), c8 = (s % (DQK / 8)) * 8;
      kreg[i] = *reinterpret_cast<const u16x8*>(Kp + (size_t)(j0 + r) * ldk + c8);
    }
    #pragma unroll
    for (int i = 0; i < 2; ++i) {
      int s = i * 256 + t;
      int d = s >> 3, c8 = (s & 7) * 8;
      vreg[i] = *reinterpret_cast<const u16x8*>(Vp + (size_t)d * 1024 + j0 + c8);
    }
  };
  auto writeKV = [&](int buf) {
    #pragma unroll
    for (int i = 0; i < KREG; ++i) {
      int s = i * 256 + t;
      int r = s / (DQK / 8), c8 = (s % (DQK / 8)) * 8;
      *reinterpret_cast<u16x8*>(&Ks[buf][r * LQ + c8]) = kreg[i];
    }
    #pragma unroll
    for (int i = 0; i < 2; ++i) {
      int s = i * 256 + t;
      int d = s >> 3, c8 = (s & 7) * 8;
      *reinterpret_cast<u16x8*>(&Vs[buf][d * 72 + c8]) = vreg[i];
    }
  };

  loadKV(0);
  writeKV(0);
  loadKV(1);
  __syncthreads();   // buffer 0 visible to all waves

  f32x4 acc_o[4] = {};
  float mrow[4] = {-1e30f, -1e30f, -1e30f, -1e30f};
  float lrow[4] = {0.f, 0.f, 0.f, 0.f};

  #pragma unroll
  for (int tile = 0; tile < 4; ++tile) {
    int cur = tile & 1;
    if (tile < 3) writeKV(cur ^ 1);        // stage next tile into other buffer (overlaps compute)
    if (tile < 2) loadKV(tile + 2);        // issue loads two tiles ahead
    // QK^T: wave w owns q rows w*16..+15
    f32x4 s_acc[4] = {};
    #pragma unroll
    for (int kk = 0; kk < DQK / 32; ++kk) {
      bf16x8 aq = *reinterpret_cast<const bf16x8*>(&Qs[(w * 16 + li) * LQ + kk * 32 + g * 8]);
      #pragma unroll
      for (int n = 0; n < 4; ++n) {
        bf16x8 bk = *reinterpret_cast<const bf16x8*>(&Ks[cur][(n * 16 + li) * LQ + kk * 32 + g * 8]);
        s_acc[n] = __builtin_amdgcn_mfma_f32_16x16x32_bf16(aq, bk, s_acc[n], 0, 0, 0);
      }
    }
    // online softmax (C-layout: row = g*4+r, col = li + n*16); scale 1/8 in exp
    #pragma unroll
    for (int r = 0; r < 4; ++r) {
      float tm = fmaxf(fmaxf(s_acc[0][r], s_acc[1][r]), fmaxf(s_acc[2][r], s_acc[3][r]));
      #pragma unroll
      for (int m = 1; m < 16; m <<= 1) tm = fmaxf(tm, __shfl_xor(tm, m, 64));
      float mn = fmaxf(mrow[r], tm);
      float sf = __expf((mrow[r] - mn) * 0.125f);
      mrow[r] = mn;
      lrow[r] *= sf;
      #pragma unroll
      for (int n = 0; n < 4; ++n) acc_o[n][r] *= sf;
      float rs = 0.f;
      #pragma unroll
      for (int n = 0; n < 4; ++n) {
        float p = __expf((s_acc[n][r] - mn) * 0.125f);
        s_acc[n][r] = p;
        rs += p;
      }
      #pragma unroll
      for (int m = 1; m < 16; m <<= 1) rs += __shfl_xor(rs, m, 64);
      lrow[r] += rs;
    }
    // P -> LDS (wave-local 16-row stripe; no barrier needed)
    #pragma unroll
    for (int n = 0; n < 4; ++n)
      #pragma unroll
      for (int r = 0; r < 4; ++r)
        Ps[(w * 16 + g * 4 + r) * 72 + n * 16 + li] = f2b_rne(s_acc[n][r]);
    // PV: A = P (q rows), B = Vs (d rows, kv k)
    #pragma unroll
    for (int kk = 0; kk < 2; ++kk) {
      bf16x8 ap = *reinterpret_cast<const bf16x8*>(&Ps[(w * 16 + li) * 72 + kk * 32 + g * 8]);
      #pragma unroll
      for (int n = 0; n < 4; ++n) {
        bf16x8 bv = *reinterpret_cast<const bf16x8*>(&Vs[cur][(n * 16 + li) * 72 + kk * 32 + g * 8]);
        acc_o[n] = __builtin_amdgcn_mfma_f32_16x16x32_bf16(ap, bv, acc_o[n], 0, 0, 0);
      }
    }
    __syncthreads();   // next-tile buffer fully written; current buffer free for reuse
  }

  size_t rowbase = (size_t)((lh0 + h) * NSPLIT + split) * 1024;
  #pragma unroll
  for (int r = 0; r < 4; ++r) {
    int qr = q0 + w * 16 + g * 4 + r;
    #pragma unroll
    for (int n = 0; n < 4; ++n)
      pout[(rowbase + qr) * 64 + n * 16 + li] = acc_o[n][r];
    if (li == 0) {
      pml[(rowbase + qr) * 2 + 0] = mrow[r];
      pml[(rowbase + qr) * 2 + 1] = lrow[r];
    }
  }
}

// ---------------- merge kv-split partials -> concat bf16 ----------------
__global__ __launch_bounds__(256) void k_fmerge(
    const float* __restrict__ pout, const float* __restrict__ pml,
    unsigned short* __restrict__ concat) {
  int rq = blockIdx.x * 4 + (threadIdx.x >> 6);   // 0..16*1024-1
  int lh = rq >> 10, q = rq & 1023;
  int d = threadIdx.x & 63;
  float m_s[NSPLIT], l_s[NSPLIT];
  float M = -1e30f;
  #pragma unroll
  for (int s = 0; s < NSPLIT; ++s) {
    size_t rb = (size_t)(lh * NSPLIT + s) * 1024 + q;
    m_s[s] = pml[rb * 2 + 0];
    l_s[s] = pml[rb * 2 + 1];
    M = fmaxf(M, m_s[s]);
  }
  float num = 0.f, den = 0.f;
  #pragma unroll
  for (int s = 0; s < NSPLIT; ++s) {
    float wgt = __expf((m_s[s] - M) * 0.125f);
    num += wgt * pout[((size_t)(lh * NSPLIT + s) * 1024 + q) * 64 + d];
    den += wgt * l_s[s];
  }
  concat[(size_t)q * DIMX + lh * 64 + d] = f2b_rne(num / den);
}

// ---------------- batched bf16 MFMA GEMM: C = A * B^T (+bias), strided ----------------
template <int HAS_BIAS, int BF16_OUT>
__global__ __launch_bounds__(256) void k_bgemm(
    const unsigned short* __restrict__ A, const unsigned short* __restrict__ B,
    void* __restrict__ Cv, const float* __restrict__ bias,
    int K, int lda, int ldb, int ldc,
    long a_batch, long b_batch, long c_batch) {
  const int LDT = 72;  // padded LDS row stride (shorts)
  __shared__ unsigned short As[64 * LDT];
  __shared__ unsigned short Bs[64 * LDT];
  int t = threadIdx.x;
  int lane = t & 63, w = t >> 6;
  int wr = w >> 1, wc = w & 1;
  int mb = blockIdx.y * 64, nb = blockIdx.x * 64;
  const unsigned short* Ab = A + (size_t)blockIdx.z * a_batch;
  const unsigned short* Bb = B + (size_t)blockIdx.z * b_batch;
  f32x4 acc[2][2] = {};
  int r0 = t >> 3;         // 0..31
  int c0 = (t & 7) * 8;    // element offset
  for (int kb = 0; kb < K; kb += 64) {
    bf16x8 av0 = *reinterpret_cast<const bf16x8*>(Ab + (size_t)(mb + r0) * lda + kb + c0);
    bf16x8 av1 = *reinterpret_cast<const bf16x8*>(Ab + (size_t)(mb + r0 + 32) * lda + kb + c0);
    bf16x8 bv0 = *reinterpret_cast<const bf16x8*>(Bb + (size_t)(nb + r0) * ldb + kb + c0);
    bf16x8 bv1 = *reinterpret_cast<const bf16x8*>(Bb + (size_t)(nb + r0 + 32) * ldb + kb + c0);
    __syncthreads();
    *reinterpret_cast<bf16x8*>(&As[r0 * LDT + c0]) = av0;
    *reinterpret_cast<bf16x8*>(&As[(r0 + 32) * LDT + c0]) = av1;
    *reinterpret_cast<bf16x8*>(&Bs[r0 * LDT + c0]) = bv0;
    *reinterpret_cast<bf16x8*>(&Bs[(r0 + 32) * LDT + c0]) = bv1;
    __syncthreads();
    #pragma unroll
    for (int kk = 0; kk < 2; ++kk) {
      bf16x8 af[2], bfr[2];
      #pragma unroll
      for (int m = 0; m < 2; ++m)
        af[m] = *reinterpret_cast<const bf16x8*>(
            &As[(wr * 32 + m * 16 + (lane & 15)) * LDT + kk * 32 + (lane >> 4) * 8]);
      #pragma unroll
      for (int n = 0; n < 2; ++n)
        bfr[n] = *reinterpret_cast<const bf16x8*>(
            &Bs[(wc * 32 + n * 16 + (lane & 15)) * LDT + kk * 32 + (lane >> 4) * 8]);
      #pragma unroll
      for (int m = 0; m < 2; ++m)
        #pragma unroll
        for (int n = 0; n < 2; ++n)
          acc[m][n] = __builtin_amdgcn_mfma_f32_16x16x32_bf16(af[m], bfr[n], acc[m][n], 0, 0, 0);
    }
  }
  #pragma unroll
  for (int m = 0; m < 2; ++m) {
    int row0 = mb + wr * 32 + m * 16 + (lane >> 4) * 4;
    #pragma unroll
    for (int n = 0; n < 2; ++n) {
      int col = nb + wc * 32 + n * 16 + (lane & 15);
      float bval = HAS_BIAS ? bias[col] : 0.0f;
      #pragma unroll
      for (int r = 0; r < 4; ++r) {
        size_t idx = (size_t)blockIdx.z * c_batch + (size_t)(row0 + r) * ldc + col;
        if (BF16_OUT) ((unsigned short*)Cv)[idx] = f2b_rne(acc[m][n][r] + bval);
        else          ((float*)Cv)[idx] = acc[m][n][r] + bval;
      }
    }
  }
}

extern "C" void kernel_launch(void* const* d_in, const int* in_sizes, int n_in,
                              void* d_out, int out_size, void* d_ws, size_t ws_size,
                              hipStream_t stream) {
  const float* x      = (const float*)d_in[0];
  const float* qsW    = (const float*)d_in[1];
  const float* qsb    = (const float*)d_in[2];
  const float* lng    = (const float*)d_in[3];
  const float* lnb    = (const float*)d_in[4];
  const float* qfreq  = (const float*)d_in[5];
  const float* qshift = (const float*)d_in[6];
  const float* Wq     = (const float*)d_in[7];
  const float* Wk     = (const float*)d_in[8];
  const float* Wv     = (const float*)d_in[9];
  const float* Wo     = (const float*)d_in[10];
  const float* bo     = (const float*)d_in[11];
  float* out = (float*)d_out;

  char* ws = (char*)d_ws;
  size_t off = 0;
  auto alloc = [&](size_t bytes) { char* p = ws + off; off += (bytes + 255) & ~(size_t)255; return p; };
  unsigned short* x_bf      = (unsigned short*)alloc((size_t)SEQ * DIMX * 2);
  unsigned short* wqkv_bf   = (unsigned short*)alloc((size_t)QKVN * DIMX * 2);
  unsigned short* wo_bf     = (unsigned short*)alloc((size_t)DIMX * DIMX * 2);
  unsigned short* concat_bf = (unsigned short*)alloc((size_t)SEQ * DIMX * 2);
  unsigned short* qkv_bf    = (unsigned short*)alloc((size_t)SEQ * QKVN * 2);
  unsigned short* qcs       = (unsigned short*)alloc((size_t)QH * SEQ * 128 * 2);
  unsigned short* kcs       = (unsigned short*)alloc((size_t)QH * SEQ * 128 * 2);
  unsigned short* vt        = (unsigned short*)alloc((size_t)TH * HD * SEQ * 2);
  unsigned short* xt        = (unsigned short*)alloc((size_t)QH * HD * SEQ * 2);
  float*          pout      = (float*)alloc((size_t)16 * NSPLIT * SEQ * 64 * 4);
  float*          pml       = (float*)alloc((size_t)16 * NSPLIT * SEQ * 2 * 4);

  k_f2b_all<<<4736, 256, 0, stream>>>(x, Wq, Wk, Wv, Wo, x_bf, wqkv_bf, wo_bf);
  k_qprep<<<QH * SEQ, 128, 0, stream>>>(x, qsW, qsb, lng, lnb, qfreq, qshift, qcs, kcs);

  // QKV projection -> bf16 qkv
  k_bgemm<0, 1><<<dim3(QKVN / 64, SEQ / 64, 1), 256, 0, stream>>>(
      x_bf, wqkv_bf, qkv_bf, nullptr, DIMX, DIMX, DIMX, QKVN, 0, 0, 0);

  k_tr64<<<dim3(16, TH), 256, 0, stream>>>(qkv_bf, QKVN, 1792, vt);
  k_tr64<<<dim3(16, QH), 256, 0, stream>>>(x_bf, DIMX, 0, xt);

  // fused attention, kv-split: quantum heads lh 0..1 (DQK=128, V=x), trad lh 2..15
  k_fattn<128><<<dim3(16, QH, NSPLIT), 256, 0, stream>>>(
      qcs, (long)SEQ * 128, 128, kcs, (long)SEQ * 128, 128, xt, (long)HD * SEQ, 0, pout, pml);
  k_fattn<64><<<dim3(16, TH, NSPLIT), 256, 0, stream>>>(
      qkv_bf, 64, QKVN, qkv_bf + 896, 64, QKVN, vt, (long)HD * SEQ, 2, pout, pml);
  k_fmerge<<<16 * SEQ / 4, 256, 0, stream>>>(pout, pml, concat_bf);

  // output projection
  k_bgemm<1, 0><<<dim3(DIMX / 64, SEQ / 64, 1), 256, 0, stream>>>(
      concat_bf, wo_bf, out, bo, DIMX, DIMX, DIMX, DIMX, 0, 0, 0);
}